// Round 5
// baseline (1259.558 us; speedup 1.0000x reference)
//
#include <hip/hip_runtime.h>
#include <math.h>

#define NT 4096      // B*T
#define DD 1024      // D == DM
#define NH 16
#define HSZ 64
#define GN_EPS 1e-5f
#define DECAY_C -0.606531f

typedef __attribute__((ext_vector_type(8))) short short8;
typedef __attribute__((ext_vector_type(4))) float float4v;

__device__ __forceinline__ float sigm(float x) { return 1.f / (1.f + __expf(-x)); }

__device__ __forceinline__ unsigned short f2bf(float f) {
    unsigned int u = __float_as_uint(f);
    u = (u + 0x7fffu + ((u >> 16) & 1u)) >> 16;
    return (unsigned short)u;
}
__device__ __forceinline__ float bf2f(unsigned short h) {
    return __uint_as_float(((unsigned int)h) << 16);
}

// 4-lane butterfly adds via DPP quad_perm (VALU pipe, ~4cyc, vs ~100cyc ds_bpermute)
__device__ __forceinline__ float dpp_add_xor1(float x) {
    int i = __float_as_int(x);
    int t = __builtin_amdgcn_update_dpp(i, i, 0xB1, 0xF, 0xF, true);  // [1,0,3,2]
    return x + __int_as_float(t);
}
__device__ __forceinline__ float dpp_add_xor2(float x) {
    int i = __float_as_int(x);
    int t = __builtin_amdgcn_update_dpp(i, i, 0x4E, 0xF, 0xF, true);  // [2,3,0,1]
    return x + __int_as_float(t);
}

// ---------------- mix + split-cast for ONE branch: x = cur + lam*(prev-cur)
__global__ __launch_bounds__(256)
void mix_split(const float* __restrict__ cur, const float* __restrict__ prev,
               const float* __restrict__ lam, ushort* __restrict__ xh,
               ushort* __restrict__ xl)
{
    const int tok = blockIdx.x;
    const int d0 = threadIdx.x * 4;
    const size_t base = (size_t)tok * DD + d0;
    float4 c = *(const float4*)(cur + base);
    float4 p = *(const float4*)(prev + base);
    float4 l = *(const float4*)(lam + d0);
    float m0 = c.x + l.x * (p.x - c.x);
    float m1 = c.y + l.y * (p.y - c.y);
    float m2 = c.z + l.z * (p.z - c.z);
    float m3 = c.w + l.w * (p.w - c.w);
    ushort4 h;
    h.x = f2bf(m0); h.y = f2bf(m1); h.z = f2bf(m2); h.w = f2bf(m3);
    *(ushort4*)(xh + base) = h;
    if (xl) {
        ushort4 lo;
        lo.x = f2bf(m0 - bf2f(h.x));
        lo.y = f2bf(m1 - bf2f(h.y));
        lo.z = f2bf(m2 - bf2f(h.z));
        lo.w = f2bf(m3 - bf2f(h.w));
        *(ushort4*)(xl + base) = lo;
    }
}

// ---------------- transpose + split-cast: W[K][N] fp32 -> Wt[N][K] hi/lo bf16
__global__ __launch_bounds__(256)
void transpose_split(const float* __restrict__ W, ushort* __restrict__ Wh,
                     ushort* __restrict__ Wl, int K, int N)
{
    __shared__ float tile[32][33];
    const int bx = blockIdx.x * 32;  // N
    const int by = blockIdx.y * 32;  // K
    const int tx = threadIdx.x, ty = threadIdx.y;  // 32 x 8
#pragma unroll
    for (int i = 0; i < 32; i += 8)
        tile[ty + i][tx] = W[(size_t)(by + ty + i) * N + bx + tx];
    __syncthreads();
#pragma unroll
    for (int i = 0; i < 32; i += 8) {
        float v = tile[tx][ty + i];
        ushort h = f2bf(v);
        size_t o = (size_t)(bx + ty + i) * K + by + tx;
        Wh[o] = h;
        if (Wl) Wl[o] = f2bf(v - bf2f(h));
    }
}

// ---------------- bf16(x3) MFMA GEMM: out[4096][N] = act(A[4096][K] @ W + bias)
__global__ __launch_bounds__(256)
void gemm_bf16s(const ushort* __restrict__ Ah, const ushort* __restrict__ Al,
                const ushort* __restrict__ Bh, const ushort* __restrict__ Bl,
                const float* __restrict__ bias,
                float* __restrict__ outF, ushort* __restrict__ outH,
                ushort* __restrict__ outL, int N, int K, int act)
{
    __shared__ ushort AsH[128 * 32];
    __shared__ ushort BsH[128 * 32];
    __shared__ ushort AsL[128 * 32];
    __shared__ ushort BsL[128 * 32];
    const bool split = (Al != nullptr);
    const int tid = threadIdx.x;
    const int rowBase = blockIdx.x * 128;
    const int colBase = blockIdx.y * 128;
    const int lane = tid & 63;
    const int wave = tid >> 6;
    const int wm = wave >> 1, wn = wave & 1;
    const int m15 = lane & 15, quad = lane >> 4;

    float4v zero4 = {0.f, 0.f, 0.f, 0.f};
    float4v acc[4][4];
#pragma unroll
    for (int i = 0; i < 4; i++)
#pragma unroll
        for (int j = 0; j < 4; j++) acc[i][j] = zero4;

    for (int k0 = 0; k0 < K; k0 += 32) {
#pragma unroll
        for (int i = 0; i < 2; i++) {
            int idx = i * 256 + tid;
            int r = idx >> 2, seg = idx & 3;
            size_t aoff = (size_t)(rowBase + r) * K + k0 + seg * 8;
            int rn = colBase + r; if (rn >= N) rn = N - 1;
            size_t boff = (size_t)rn * K + k0 + seg * 8;
            *(uint4*)(AsH + idx * 8) = *(const uint4*)(Ah + aoff);
            *(uint4*)(BsH + idx * 8) = *(const uint4*)(Bh + boff);
            if (split) {
                *(uint4*)(AsL + idx * 8) = *(const uint4*)(Al + aoff);
                *(uint4*)(BsL + idx * 8) = *(const uint4*)(Bl + boff);
            }
        }
        __syncthreads();
        short8 ah[4], bh[4];
#pragma unroll
        for (int mi = 0; mi < 4; mi++)
            ah[mi] = *(const short8*)(AsH + (wm * 64 + mi * 16 + m15) * 32 + quad * 8);
#pragma unroll
        for (int ni = 0; ni < 4; ni++)
            bh[ni] = *(const short8*)(BsH + (wn * 64 + ni * 16 + m15) * 32 + quad * 8);
        if (split) {
            short8 al[4], bl[4];
#pragma unroll
            for (int mi = 0; mi < 4; mi++)
                al[mi] = *(const short8*)(AsL + (wm * 64 + mi * 16 + m15) * 32 + quad * 8);
#pragma unroll
            for (int ni = 0; ni < 4; ni++)
                bl[ni] = *(const short8*)(BsL + (wn * 64 + ni * 16 + m15) * 32 + quad * 8);
#pragma unroll
            for (int mi = 0; mi < 4; mi++)
#pragma unroll
                for (int ni = 0; ni < 4; ni++) {
                    acc[mi][ni] = __builtin_amdgcn_mfma_f32_16x16x32_bf16(al[mi], bh[ni], acc[mi][ni], 0, 0, 0);
                    acc[mi][ni] = __builtin_amdgcn_mfma_f32_16x16x32_bf16(ah[mi], bl[ni], acc[mi][ni], 0, 0, 0);
                    acc[mi][ni] = __builtin_amdgcn_mfma_f32_16x16x32_bf16(ah[mi], bh[ni], acc[mi][ni], 0, 0, 0);
                }
        } else {
#pragma unroll
            for (int mi = 0; mi < 4; mi++)
#pragma unroll
                for (int ni = 0; ni < 4; ni++)
                    acc[mi][ni] = __builtin_amdgcn_mfma_f32_16x16x32_bf16(ah[mi], bh[ni], acc[mi][ni], 0, 0, 0);
        }
        __syncthreads();
    }

#pragma unroll
    for (int mi = 0; mi < 4; mi++) {
#pragma unroll
        for (int ni = 0; ni < 4; ni++) {
            int col = colBase + wn * 64 + ni * 16 + m15;
            if (col < N) {
                float bv = bias ? bias[col] : 0.f;
#pragma unroll
                for (int r = 0; r < 4; r++) {
                    int row = rowBase + wm * 64 + mi * 16 + quad * 4 + r;
                    float v = acc[mi][ni][r] + bv;
                    if (act == 1) v = tanhf(v);
                    else if (act == 2) v = sigm(v);
                    size_t o = (size_t)row * N + col;
                    if (outF) outF[o] = v;
                    else {
                        ushort h = f2bf(v);
                        outH[o] = h;
                        if (outL) outL[o] = f2bf(v - bf2f(h));
                    }
                }
            }
        }
    }
}

// ---------------- elementwise stage 1 (fp32)
__global__ __launch_bounds__(256)
void elemwise1(const float* __restrict__ r_buf, float* __restrict__ wl_buf,
               float* __restrict__ k_buf, float* __restrict__ v_buf,
               float* __restrict__ kkn_buf, const float* __restrict__ a_buf,
               const float* __restrict__ vg_buf, const float* __restrict__ vfirst,
               const float* __restrict__ kkw, const float* __restrict__ kaw,
               const float* __restrict__ rkw, float* __restrict__ rk_sum)
{
    const int tok = blockIdx.x;
    const int tid = threadIdx.x;
    const int d0 = tid * 4;
    const size_t base = (size_t)tok * DD + d0;

    float4 k0 = *(const float4*)(k_buf + base);
    float4 a4 = *(const float4*)(a_buf + base);
    float4 wl = *(const float4*)(wl_buf + base);
    float4 v0 = *(const float4*)(v_buf + base);
    float4 vg = *(const float4*)(vg_buf + base);
    float4 vf = *(const float4*)(vfirst + base);
    float4 r4 = *(const float4*)(r_buf + base);
    float4 kkc = *(const float4*)(kkw + d0);
    float4 kac = *(const float4*)(kaw + d0);
    float4 rkc = *(const float4*)(rkw + d0);

    float kk0 = k0.x * kkc.x, kk1 = k0.y * kkc.y, kk2 = k0.z * kkc.z, kk3 = k0.w * kkc.w;
    float ss = kk0 * kk0 + kk1 * kk1 + kk2 * kk2 + kk3 * kk3;
    ss += __shfl_xor(ss, 1); ss += __shfl_xor(ss, 2);
    ss += __shfl_xor(ss, 4); ss += __shfl_xor(ss, 8);
    float rn = rsqrtf(ss);
    float4 kkn = { kk0 * rn, kk1 * rn, kk2 * rn, kk3 * rn };
    *(float4*)(kkn_buf + base) = kkn;

    float4 kf;
    kf.x = k0.x * (1.f + (a4.x - 1.f) * kac.x);
    kf.y = k0.y * (1.f + (a4.y - 1.f) * kac.y);
    kf.z = k0.z * (1.f + (a4.z - 1.f) * kac.z);
    kf.w = k0.w * (1.f + (a4.w - 1.f) * kac.w);
    *(float4*)(k_buf + base) = kf;

    float rk = r4.x * kf.x * rkc.x + r4.y * kf.y * rkc.y + r4.z * kf.z * rkc.z + r4.w * kf.w * rkc.w;
    rk += __shfl_xor(rk, 1); rk += __shfl_xor(rk, 2);
    rk += __shfl_xor(rk, 4); rk += __shfl_xor(rk, 8);
    if ((tid & 15) == 0) rk_sum[(size_t)tok * NH + (tid >> 4)] = rk;

    float4 vfin;
    vfin.x = v0.x + (vf.x - v0.x) * vg.x;
    vfin.y = v0.y + (vf.y - v0.y) * vg.y;
    vfin.z = v0.z + (vf.z - v0.z) * vg.z;
    vfin.w = v0.w + (vf.w - v0.w) * vg.w;
    *(float4*)(v_buf + base) = vfin;

    float4 wd;
    wd.x = __expf(DECAY_C * sigm(wl.x));
    wd.y = __expf(DECAY_C * sigm(wl.y));
    wd.z = __expf(DECAY_C * sigm(wl.z));
    wd.w = __expf(DECAY_C * sigm(wl.w));
    *(float4*)(wl_buf + base) = wd;
}

// ---------------- sequential scan: 16 rows x 4 lanes, 16 state elems/lane.
// grid (64 bh, 4 rowgroups) x 64 threads (1 wave). Chunk of 16 steps staged in
// LDS; reductions via 2-stage DPP quad_perm butterflies (VALU pipe, no LDS).
__global__ __launch_bounds__(64)
void scan_kernel(const float* __restrict__ r_buf, const float* __restrict__ w_buf,
                 const float* __restrict__ k_buf, const float* __restrict__ kkn_buf,
                 const float* __restrict__ a_buf, const float* __restrict__ v_buf,
                 float* __restrict__ out_scan, float* __restrict__ state_out)
{
    __shared__ float vec[16][5][64];   // [t][r|w|k|kk|a][64]  20 KB
    __shared__ float vbuf[16][16];     // [t][16 rows]
    __shared__ float ybuf[16][16];     // [t][16 rows]
    const int bh = blockIdx.x;
    const int rg = blockIdx.y;
    const int b = bh >> 4, h = bh & 15;
    const int tid = threadIdx.x;
    const int row = tid >> 2, l4 = tid & 3;
    const int e0 = l4 * 16;                 // this lane's 16 k-elems
    const int rowbase = rg * 16;
    const size_t tok0 = ((size_t)b * 1024) * DD + h * HSZ;

    const int lane16 = tid & 15, g4 = tid >> 4;   // staging map
    const int ft = tid >> 2, fl = (tid & 3) * 4;  // flush map

    float s[16];
#pragma unroll
    for (int j = 0; j < 16; j++) s[j] = 0.f;

    for (int c = 0; c < 64; c++) {
        if (c > 0) {
            float4 yv = *(float4*)&ybuf[ft][fl];
            *(float4*)(out_scan + tok0 + (size_t)((c - 1) * 16 + ft) * DD + rowbase + fl) = yv;
        }
#pragma unroll
        for (int i = 0; i < 20; i++) {
            int idx = i * 4 + g4;                 // 0..79 = (j,t)
            int t = idx & 15, j = idx >> 4;
            const float* bs = (j == 0) ? r_buf : (j == 1) ? w_buf : (j == 2) ? k_buf
                              : (j == 3) ? kkn_buf : a_buf;
            *(float4*)&vec[t][j][lane16 * 4] =
                *(const float4*)(bs + tok0 + (size_t)(c * 16 + t) * DD + lane16 * 4);
        }
        *(float4*)&vbuf[ft][fl] =
            *(const float4*)(v_buf + tok0 + (size_t)(c * 16 + ft) * DD + rowbase + fl);
        __syncthreads();

        for (int t = 0; t < 16; t++) {
            const float* vp = &vec[t][0][0];
            float qv[16], wv[16], kv[16], av[16], rv[16];
#pragma unroll
            for (int i = 0; i < 4; i++)
                *(float4*)&qv[i * 4] = *(const float4*)(vp + 192 + e0 + i * 4);  // kk

            float sacc0 = 0.f, sacc1 = 0.f, sacc2 = 0.f, sacc3 = 0.f;
#pragma unroll
            for (int jj = 0; jj < 16; jj += 4) {
                sacc0 += s[jj + 0] * qv[jj + 0];
                sacc1 += s[jj + 1] * qv[jj + 1];
                sacc2 += s[jj + 2] * qv[jj + 2];
                sacc3 += s[jj + 3] * qv[jj + 3];
            }
            float sa = (sacc0 + sacc1) + (sacc2 + sacc3);
            sa = dpp_add_xor1(sa);
            sa = dpp_add_xor2(sa);
            sa = -sa;  // at = -kk

#pragma unroll
            for (int i = 0; i < 4; i++) {
                *(float4*)&wv[i * 4] = *(const float4*)(vp + 64 + e0 + i * 4);
                *(float4*)&kv[i * 4] = *(const float4*)(vp + 128 + e0 + i * 4);
                *(float4*)&av[i * 4] = *(const float4*)(vp + 256 + e0 + i * 4);
                *(float4*)&rv[i * 4] = *(const float4*)(vp + e0 + i * 4);
            }
            float vv = vbuf[t][row];

            float yacc0 = 0.f, yacc1 = 0.f, yacc2 = 0.f, yacc3 = 0.f;
#pragma unroll
            for (int jj = 0; jj < 16; jj += 4) {
                s[jj + 0] = s[jj + 0] * wv[jj + 0] + sa * (qv[jj + 0] * av[jj + 0]) + vv * kv[jj + 0];
                s[jj + 1] = s[jj + 1] * wv[jj + 1] + sa * (qv[jj + 1] * av[jj + 1]) + vv * kv[jj + 1];
                s[jj + 2] = s[jj + 2] * wv[jj + 2] + sa * (qv[jj + 2] * av[jj + 2]) + vv * kv[jj + 2];
                s[jj + 3] = s[jj + 3] * wv[jj + 3] + sa * (qv[jj + 3] * av[jj + 3]) + vv * kv[jj + 3];
                yacc0 += s[jj + 0] * rv[jj + 0];
                yacc1 += s[jj + 1] * rv[jj + 1];
                yacc2 += s[jj + 2] * rv[jj + 2];
                yacc3 += s[jj + 3] * rv[jj + 3];
            }
            float y = (yacc0 + yacc1) + (yacc2 + yacc3);
            y = dpp_add_xor1(y);
            y = dpp_add_xor2(y);
            if (l4 == 0) ybuf[t][row] = y;
        }
        __syncthreads();
    }

    // final flush (chunk 63)
    {
        float4 yv = *(float4*)&ybuf[ft][fl];
        *(float4*)(out_scan + tok0 + (size_t)(1008 + ft) * DD + rowbase + fl) = yv;
    }

    float* so = state_out + ((size_t)(b * NH + h) * HSZ + rowbase + row) * HSZ + e0;
#pragma unroll
    for (int i = 0; i < 4; i++)
        *(float4*)(so + i * 4) = *(float4*)&s[i * 4];
}

// ---------------- stage 2: GroupNorm + residual + gate -> z (plain bf16)
__global__ __launch_bounds__(256)
void elemwise2(const float* __restrict__ out_scan, const float* __restrict__ rk_sum,
               const float* __restrict__ v_buf, const float* __restrict__ g_buf,
               const float* __restrict__ gscale, const float* __restrict__ gbias,
               ushort* __restrict__ z_buf)
{
    const int tok = blockIdx.x;
    const int tid = threadIdx.x;
    const int d0 = tid * 4;
    const size_t base = (size_t)tok * DD + d0;

    float4 o = *(const float4*)(out_scan + base);
    float sm = o.x + o.y + o.z + o.w;
    float ss = o.x * o.x + o.y * o.y + o.z * o.z + o.w * o.w;
    sm += __shfl_xor(sm, 1); sm += __shfl_xor(sm, 2);
    sm += __shfl_xor(sm, 4); sm += __shfl_xor(sm, 8);
    ss += __shfl_xor(ss, 1); ss += __shfl_xor(ss, 2);
    ss += __shfl_xor(ss, 4); ss += __shfl_xor(ss, 8);
    float mu = sm * (1.f / 64.f);
    float var = ss * (1.f / 64.f) - mu * mu;
    float rs = rsqrtf(var + GN_EPS);
    float rk = rk_sum[(size_t)tok * NH + (tid >> 4)];

    float4 v4 = *(const float4*)(v_buf + base);
    float4 g4 = *(const float4*)(g_buf + base);
    float4 gs = *(const float4*)(gscale + d0);
    float4 gb = *(const float4*)(gbias + d0);
    ushort4 z;
    z.x = f2bf(((o.x - mu) * rs * gs.x + gb.x + rk * v4.x) * g4.x);
    z.y = f2bf(((o.y - mu) * rs * gs.y + gb.y + rk * v4.y) * g4.y);
    z.z = f2bf(((o.z - mu) * rs * gs.z + gb.z + rk * v4.z) * g4.z);
    z.w = f2bf(((o.w - mu) * rs * gs.w + gb.w + rk * v4.w) * g4.w);
    *(ushort4*)(z_buf + base) = z;
}

extern "C" void kernel_launch(void* const* d_in, const int* in_sizes, int n_in,
                              void* d_out, int out_size, void* d_ws, size_t ws_size,
                              hipStream_t stream) {
    const float* cur    = (const float*)d_in[0];
    const float* prev   = (const float*)d_in[1];
    const float* vfirst = (const float*)d_in[2];
    const float* rwkvag = (const float*)d_in[3];
    const float* rw_W   = (const float*)d_in[4];
    const float* w1     = (const float*)d_in[5];
    const float* w2     = (const float*)d_in[6];
    const float* w2_b   = (const float*)d_in[7];
    const float* kw_W   = (const float*)d_in[8];
    const float* vw_W   = (const float*)d_in[9];
    const float* a1     = (const float*)d_in[10];
    const float* a2     = (const float*)d_in[11];
    const float* a2_b   = (const float*)d_in[12];
    const float* v1     = (const float*)d_in[13];
    const float* v2     = (const float*)d_in[14];
    const float* v2_b   = (const float*)d_in[15];
    const float* g1     = (const float*)d_in[16];
    const float* g2     = (const float*)d_in[17];
    const float* g2_b   = (const float*)d_in[18];
    const float* k_k    = (const float*)d_in[19];
    const float* k_a    = (const float*)d_in[20];
    const float* r_k    = (const float*)d_in[21];
    const float* gn_s   = (const float*)d_in[22];
    const float* gn_b   = (const float*)d_in[23];
    const float* out_W  = (const float*)d_in[24];

    float* out = (float*)d_out;
    float* y_out = out;                                  // 4096*1024 fp32
    float* state_out = out + (size_t)NT * DD;            // 4*16*64*64 fp32
    float* vf_out = state_out + (size_t)4 * NH * HSZ * HSZ;

    // ---- workspace carve (float units). ~166 MB total.
    float* p = (float*)d_ws;
    const size_t big = (size_t)NT * DD;   // 4,194,304 floats
    const size_t half = big / 2;          // one big bf16 array, in float units
    float* r_buf = p;   p += big;
    float* w_buf = p;   p += big;   // wl -> wdec in place
    float* k_buf = p;   p += big;   // k0 -> k final in place
    float* v_buf = p;   p += big;   // v0 -> v final in place
    float* kkn_buf = p; p += big;
    float* a_buf = p;   p += big;
    float* vg_buf = p;  p += big;   // dead after elemwise1 -> reused as out_scan
    float* os_buf = vg_buf;
    float* g_buf = p;   p += big;
    ushort* xh = (ushort*)p; p += half;   // shared per-branch mix scratch
    ushort* xl = (ushort*)p; p += half;
    ushort* z_bf = xh;                    // z overlays xh (x dead post stage-1)
    const size_t WBIG = 524288;           // 1024x1024 bf16, float units
    ushort* rwTh = (ushort*)p; p += WBIG;  ushort* rwTl = (ushort*)p; p += WBIG;
    ushort* kwTh = (ushort*)p; p += WBIG;  ushort* kwTl = (ushort*)p; p += WBIG;
    ushort* vwTh = (ushort*)p; p += WBIG;  ushort* vwTl = (ushort*)p; p += WBIG;
    ushort* outTh = (ushort*)p; p += WBIG;              // plain (no lo)
    ushort* w1Th = (ushort*)p; p += 32768; ushort* w1Tl = (ushort*)p; p += 32768;
    ushort* a1Th = (ushort*)p; p += 32768; ushort* a1Tl = (ushort*)p; p += 32768;
    ushort* v1Th = (ushort*)p; p += 16384; ushort* v1Tl = (ushort*)p; p += 16384;
    ushort* g1Th = (ushort*)p; p += 65536;              // plain
    ushort* w2Th = (ushort*)p; p += 32768; ushort* w2Tl = (ushort*)p; p += 32768;
    ushort* a2Th = (ushort*)p; p += 32768; ushort* a2Tl = (ushort*)p; p += 32768;
    ushort* v2Th = (ushort*)p; p += 16384; ushort* v2Tl = (ushort*)p; p += 16384;
    ushort* g2Th = (ushort*)p; p += 65536;              // plain
    ushort* hwh = (ushort*)p; p += 131072; ushort* hwl = (ushort*)p; p += 131072;
    ushort* hah = (ushort*)p; p += 131072; ushort* hal = (ushort*)p; p += 131072;
    ushort* hvh = (ushort*)p; p += 65536;  ushort* hvl = (ushort*)p; p += 65536;
    ushort* hgh = (ushort*)p; p += 262144;              // plain
    float* rks_buf = p;        p += 65536;

    dim3 blk(256);
    dim3 t32x8(32, 8);

    // ---- weight transposes (split except g path / out_W)
    transpose_split<<<dim3(32, 32), t32x8, 0, stream>>>(rw_W, rwTh, rwTl, 1024, 1024);
    transpose_split<<<dim3(32, 32), t32x8, 0, stream>>>(kw_W, kwTh, kwTl, 1024, 1024);
    transpose_split<<<dim3(32, 32), t32x8, 0, stream>>>(vw_W, vwTh, vwTl, 1024, 1024);
    transpose_split<<<dim3(32, 32), t32x8, 0, stream>>>(out_W, outTh, nullptr, 1024, 1024);
    transpose_split<<<dim3(2, 32), t32x8, 0, stream>>>(w1, w1Th, w1Tl, 1024, 64);
    transpose_split<<<dim3(2, 32), t32x8, 0, stream>>>(a1, a1Th, a1Tl, 1024, 64);
    transpose_split<<<dim3(1, 32), t32x8, 0, stream>>>(v1, v1Th, v1Tl, 1024, 32);
    transpose_split<<<dim3(4, 32), t32x8, 0, stream>>>(g1, g1Th, nullptr, 1024, 128);
    transpose_split<<<dim3(32, 2), t32x8, 0, stream>>>(w2, w2Th, w2Tl, 64, 1024);
    transpose_split<<<dim3(32, 2), t32x8, 0, stream>>>(a2, a2Th, a2Tl, 64, 1024);
    transpose_split<<<dim3(32, 1), t32x8, 0, stream>>>(v2, v2Th, v2Tl, 32, 1024);
    transpose_split<<<dim3(32, 4), t32x8, 0, stream>>>(g2, g2Th, nullptr, 128, 1024);

    dim3 gBig(32, 8), gN1(32, 1);

    // ---- branch r
    mix_split<<<NT, blk, 0, stream>>>(cur, prev, rwkvag + 0 * DD, xh, xl);
    gemm_bf16s<<<gBig, blk, 0, stream>>>(xh, xl, rwTh, rwTl, nullptr, r_buf, nullptr, nullptr, 1024, 1024, 0);
    // ---- branch w (LoRA stage 1, tanh, split hidden)
    mix_split<<<NT, blk, 0, stream>>>(cur, prev, rwkvag + 1 * DD, xh, xl);
    gemm_bf16s<<<gN1, blk, 0, stream>>>(xh, xl, w1Th, w1Tl, nullptr, nullptr, hwh, hwl, 64, 1024, 1);
    // ---- branch k
    mix_split<<<NT, blk, 0, stream>>>(cur, prev, rwkvag + 2 * DD, xh, xl);
    gemm_bf16s<<<gBig, blk, 0, stream>>>(xh, xl, kwTh, kwTl, nullptr, k_buf, nullptr, nullptr, 1024, 1024, 0);
    // ---- branch v (big GEMM + v-gate LoRA stage 1)
    mix_split<<<NT, blk, 0, stream>>>(cur, prev, rwkvag + 3 * DD, xh, xl);
    gemm_bf16s<<<gBig, blk, 0, stream>>>(xh, xl, vwTh, vwTl, nullptr, v_buf, nullptr, nullptr, 1024, 1024, 0);
    gemm_bf16s<<<gN1, blk, 0, stream>>>(xh, xl, v1Th, v1Tl, nullptr, nullptr, hvh, hvl, 32, 1024, 0);
    // ---- branch a (LoRA stage 1)
    mix_split<<<NT, blk, 0, stream>>>(cur, prev, rwkvag + 4 * DD, xh, xl);
    gemm_bf16s<<<gN1, blk, 0, stream>>>(xh, xl, a1Th, a1Tl, nullptr, nullptr, hah, hal, 64, 1024, 0);
    // ---- branch g (plain bf16 path, sigmoid hidden)
    mix_split<<<NT, blk, 0, stream>>>(cur, prev, rwkvag + 5 * DD, xh, nullptr);
    gemm_bf16s<<<gN1, blk, 0, stream>>>(xh, nullptr, g1Th, nullptr, nullptr, nullptr, hgh, nullptr, 128, 1024, 2);

    // ---- LoRA stage 2
    gemm_bf16s<<<gBig, blk, 0, stream>>>(hwh, hwl, w2Th, w2Tl, w2_b, w_buf, nullptr, nullptr, 1024, 64, 0);
    gemm_bf16s<<<gBig, blk, 0, stream>>>(hah, hal, a2Th, a2Tl, a2_b, a_buf, nullptr, nullptr, 1024, 64, 2);
    gemm_bf16s<<<gBig, blk, 0, stream>>>(hvh, hvl, v2Th, v2Tl, v2_b, vg_buf, nullptr, nullptr, 1024, 32, 2);
    gemm_bf16s<<<gBig, blk, 0, stream>>>(hgh, nullptr, g2Th, nullptr, g2_b, g_buf, nullptr, nullptr, 1024, 128, 0);

    // ---- elementwise + scan + epilogue
    elemwise1<<<NT, blk, 0, stream>>>(r_buf, w_buf, k_buf, v_buf, kkn_buf, a_buf,
                                      vg_buf, vfirst, k_k, k_a, r_k, rks_buf);

    scan_kernel<<<dim3(64, 4), dim3(64), 0, stream>>>(r_buf, w_buf, k_buf, kkn_buf, a_buf, v_buf,
                                                      os_buf, state_out);

    elemwise2<<<NT, blk, 0, stream>>>(os_buf, rks_buf, v_buf, g_buf, gn_s, gn_b, z_bf);

    // ---- y = z @ out_W (plain bf16)
    gemm_bf16s<<<gBig, blk, 0, stream>>>(z_bf, nullptr, outTh, nullptr, nullptr, y_out, nullptr, nullptr, 1024, 1024, 0);

    // ---- v_first passthrough
    hipMemcpyAsync(vf_out, vfirst, (size_t)NT * DD * sizeof(float),
                   hipMemcpyDeviceToDevice, stream);
}

// Round 6
// 875.476 us; speedup vs baseline: 1.4387x; 1.4387x over previous
//
#include <hip/hip_runtime.h>
#include <math.h>

#define NT 4096      // B*T
#define DD 1024      // D == DM
#define NH 16
#define HSZ 64
#define GN_EPS 1e-5f
#define DECAY_C -0.606531f

typedef __attribute__((ext_vector_type(8))) short short8;
typedef __attribute__((ext_vector_type(4))) float float4v;

#define GLB(p) ((const __attribute__((address_space(1))) void*)(p))
#define LDS(p) ((__attribute__((address_space(3))) void*)(p))

__device__ __forceinline__ float sigm(float x) { return 1.f / (1.f + __expf(-x)); }

__device__ __forceinline__ unsigned short f2bf(float f) {
    unsigned int u = __float_as_uint(f);
    u = (u + 0x7fffu + ((u >> 16) & 1u)) >> 16;
    return (unsigned short)u;
}
__device__ __forceinline__ float bf2f(unsigned short h) {
    return __uint_as_float(((unsigned int)h) << 16);
}

// Full sum across each 16-lane row via DPP row_ror rotate-adds (VALU pipe only,
// no LDS/bpermute). Every lane ends with the row total.
__device__ __forceinline__ float row_sum16(float x) {
    int t;
    t = __builtin_amdgcn_update_dpp(0, __float_as_int(x), 0x128, 0xF, 0xF, true); // ror 8
    x += __int_as_float(t);
    t = __builtin_amdgcn_update_dpp(0, __float_as_int(x), 0x124, 0xF, 0xF, true); // ror 4
    x += __int_as_float(t);
    t = __builtin_amdgcn_update_dpp(0, __float_as_int(x), 0x122, 0xF, 0xF, true); // ror 2
    x += __int_as_float(t);
    t = __builtin_amdgcn_update_dpp(0, __float_as_int(x), 0x121, 0xF, 0xF, true); // ror 1
    x += __int_as_float(t);
    return x;
}

// ---------------- mix + split-cast for ONE branch: x = cur + lam*(prev-cur)
__global__ __launch_bounds__(256)
void mix_split(const float* __restrict__ cur, const float* __restrict__ prev,
               const float* __restrict__ lam, ushort* __restrict__ xh,
               ushort* __restrict__ xl)
{
    const int tok = blockIdx.x;
    const int d0 = threadIdx.x * 4;
    const size_t base = (size_t)tok * DD + d0;
    float4 c = *(const float4*)(cur + base);
    float4 p = *(const float4*)(prev + base);
    float4 l = *(const float4*)(lam + d0);
    float m0 = c.x + l.x * (p.x - c.x);
    float m1 = c.y + l.y * (p.y - c.y);
    float m2 = c.z + l.z * (p.z - c.z);
    float m3 = c.w + l.w * (p.w - c.w);
    ushort4 h;
    h.x = f2bf(m0); h.y = f2bf(m1); h.z = f2bf(m2); h.w = f2bf(m3);
    *(ushort4*)(xh + base) = h;
    if (xl) {
        ushort4 lo;
        lo.x = f2bf(m0 - bf2f(h.x));
        lo.y = f2bf(m1 - bf2f(h.y));
        lo.z = f2bf(m2 - bf2f(h.z));
        lo.w = f2bf(m3 - bf2f(h.w));
        *(ushort4*)(xl + base) = lo;
    }
}

// ---------------- transpose + split-cast: W[K][N] fp32 -> Wt[N][K] hi/lo bf16
__global__ __launch_bounds__(256)
void transpose_split(const float* __restrict__ W, ushort* __restrict__ Wh,
                     ushort* __restrict__ Wl, int K, int N)
{
    __shared__ float tile[32][33];
    const int bx = blockIdx.x * 32;  // N
    const int by = blockIdx.y * 32;  // K
    const int tx = threadIdx.x, ty = threadIdx.y;  // 32 x 8
#pragma unroll
    for (int i = 0; i < 32; i += 8)
        tile[ty + i][tx] = W[(size_t)(by + ty + i) * N + bx + tx];
    __syncthreads();
#pragma unroll
    for (int i = 0; i < 32; i += 8) {
        float v = tile[tx][ty + i];
        ushort h = f2bf(v);
        size_t o = (size_t)(bx + ty + i) * K + by + tx;
        Wh[o] = h;
        if (Wl) Wl[o] = f2bf(v - bf2f(h));
    }
}

// ---------------- bf16(x3) MFMA GEMM: out[4096][N] = act(A[4096][K] @ W + bias)
// Staging via async global_load_lds (16B, wave-uniform base + lane*16).
__global__ __launch_bounds__(256)
void gemm_bf16s(const ushort* __restrict__ Ah, const ushort* __restrict__ Al,
                const ushort* __restrict__ Bh, const ushort* __restrict__ Bl,
                const float* __restrict__ bias,
                float* __restrict__ outF, ushort* __restrict__ outH,
                ushort* __restrict__ outL, int N, int K, int act)
{
    __shared__ ushort AsH[128 * 32];
    __shared__ ushort BsH[128 * 32];
    __shared__ ushort AsL[128 * 32];
    __shared__ ushort BsL[128 * 32];
    const bool split = (Al != nullptr);
    const int tid = threadIdx.x;
    const int rowBase = blockIdx.x * 128;
    const int colBase = blockIdx.y * 128;
    const int lane = tid & 63;
    const int wave = tid >> 6;
    const int wm = wave >> 1, wn = wave & 1;
    const int m15 = lane & 15, quad = lane >> 4;

    float4v zero4 = {0.f, 0.f, 0.f, 0.f};
    float4v acc[4][4];
#pragma unroll
    for (int i = 0; i < 4; i++)
#pragma unroll
        for (int j = 0; j < 4; j++) acc[i][j] = zero4;

    for (int k0 = 0; k0 < K; k0 += 32) {
#pragma unroll
        for (int i = 0; i < 2; i++) {
            int idx = i * 256 + tid;
            int r = idx >> 2, seg = idx & 3;
            size_t aoff = (size_t)(rowBase + r) * K + k0 + seg * 8;
            int rn = colBase + r; if (rn >= N) rn = N - 1;
            size_t boff = (size_t)rn * K + k0 + seg * 8;
            int dst = (i * 256 + (tid & ~63)) * 8;   // wave-uniform LDS base (ushorts)
            __builtin_amdgcn_global_load_lds(GLB(Ah + aoff), LDS(AsH + dst), 16, 0, 0);
            __builtin_amdgcn_global_load_lds(GLB(Bh + boff), LDS(BsH + dst), 16, 0, 0);
            if (split) {
                __builtin_amdgcn_global_load_lds(GLB(Al + aoff), LDS(AsL + dst), 16, 0, 0);
                __builtin_amdgcn_global_load_lds(GLB(Bl + boff), LDS(BsL + dst), 16, 0, 0);
            }
        }
        __syncthreads();
        short8 ah[4], bh[4];
#pragma unroll
        for (int mi = 0; mi < 4; mi++)
            ah[mi] = *(const short8*)(AsH + (wm * 64 + mi * 16 + m15) * 32 + quad * 8);
#pragma unroll
        for (int ni = 0; ni < 4; ni++)
            bh[ni] = *(const short8*)(BsH + (wn * 64 + ni * 16 + m15) * 32 + quad * 8);
        if (split) {
            short8 al[4], bl[4];
#pragma unroll
            for (int mi = 0; mi < 4; mi++)
                al[mi] = *(const short8*)(AsL + (wm * 64 + mi * 16 + m15) * 32 + quad * 8);
#pragma unroll
            for (int ni = 0; ni < 4; ni++)
                bl[ni] = *(const short8*)(BsL + (wn * 64 + ni * 16 + m15) * 32 + quad * 8);
#pragma unroll
            for (int mi = 0; mi < 4; mi++)
#pragma unroll
                for (int ni = 0; ni < 4; ni++) {
                    acc[mi][ni] = __builtin_amdgcn_mfma_f32_16x16x32_bf16(al[mi], bh[ni], acc[mi][ni], 0, 0, 0);
                    acc[mi][ni] = __builtin_amdgcn_mfma_f32_16x16x32_bf16(ah[mi], bl[ni], acc[mi][ni], 0, 0, 0);
                    acc[mi][ni] = __builtin_amdgcn_mfma_f32_16x16x32_bf16(ah[mi], bh[ni], acc[mi][ni], 0, 0, 0);
                }
        } else {
#pragma unroll
            for (int mi = 0; mi < 4; mi++)
#pragma unroll
                for (int ni = 0; ni < 4; ni++)
                    acc[mi][ni] = __builtin_amdgcn_mfma_f32_16x16x32_bf16(ah[mi], bh[ni], acc[mi][ni], 0, 0, 0);
        }
        __syncthreads();
    }

#pragma unroll
    for (int mi = 0; mi < 4; mi++) {
#pragma unroll
        for (int ni = 0; ni < 4; ni++) {
            int col = colBase + wn * 64 + ni * 16 + m15;
            if (col < N) {
                float bv = bias ? bias[col] : 0.f;
#pragma unroll
                for (int r = 0; r < 4; r++) {
                    int row = rowBase + wm * 64 + mi * 16 + quad * 4 + r;
                    float v = acc[mi][ni][r] + bv;
                    if (act == 1) v = tanhf(v);
                    else if (act == 2) v = sigm(v);
                    size_t o = (size_t)row * N + col;
                    if (outF) outF[o] = v;
                    else {
                        ushort h = f2bf(v);
                        outH[o] = h;
                        if (outL) outL[o] = f2bf(v - bf2f(h));
                    }
                }
            }
        }
    }
}

// ---------------- elementwise stage 1 (fp32)
__global__ __launch_bounds__(256)
void elemwise1(const float* __restrict__ r_buf, float* __restrict__ wl_buf,
               float* __restrict__ k_buf, float* __restrict__ v_buf,
               float* __restrict__ kkn_buf, const float* __restrict__ a_buf,
               const float* __restrict__ vg_buf, const float* __restrict__ vfirst,
               const float* __restrict__ kkw, const float* __restrict__ kaw,
               const float* __restrict__ rkw, float* __restrict__ rk_sum)
{
    const int tok = blockIdx.x;
    const int tid = threadIdx.x;
    const int d0 = tid * 4;
    const size_t base = (size_t)tok * DD + d0;

    float4 k0 = *(const float4*)(k_buf + base);
    float4 a4 = *(const float4*)(a_buf + base);
    float4 wl = *(const float4*)(wl_buf + base);
    float4 v0 = *(const float4*)(v_buf + base);
    float4 vg = *(const float4*)(vg_buf + base);
    float4 vf = *(const float4*)(vfirst + base);
    float4 r4 = *(const float4*)(r_buf + base);
    float4 kkc = *(const float4*)(kkw + d0);
    float4 kac = *(const float4*)(kaw + d0);
    float4 rkc = *(const float4*)(rkw + d0);

    float kk0 = k0.x * kkc.x, kk1 = k0.y * kkc.y, kk2 = k0.z * kkc.z, kk3 = k0.w * kkc.w;
    float ss = kk0 * kk0 + kk1 * kk1 + kk2 * kk2 + kk3 * kk3;
    ss += __shfl_xor(ss, 1); ss += __shfl_xor(ss, 2);
    ss += __shfl_xor(ss, 4); ss += __shfl_xor(ss, 8);
    float rn = rsqrtf(ss);
    float4 kkn = { kk0 * rn, kk1 * rn, kk2 * rn, kk3 * rn };
    *(float4*)(kkn_buf + base) = kkn;

    float4 kf;
    kf.x = k0.x * (1.f + (a4.x - 1.f) * kac.x);
    kf.y = k0.y * (1.f + (a4.y - 1.f) * kac.y);
    kf.z = k0.z * (1.f + (a4.z - 1.f) * kac.z);
    kf.w = k0.w * (1.f + (a4.w - 1.f) * kac.w);
    *(float4*)(k_buf + base) = kf;

    float rk = r4.x * kf.x * rkc.x + r4.y * kf.y * rkc.y + r4.z * kf.z * rkc.z + r4.w * kf.w * rkc.w;
    rk += __shfl_xor(rk, 1); rk += __shfl_xor(rk, 2);
    rk += __shfl_xor(rk, 4); rk += __shfl_xor(rk, 8);
    if ((tid & 15) == 0) rk_sum[(size_t)tok * NH + (tid >> 4)] = rk;

    float4 vfin;
    vfin.x = v0.x + (vf.x - v0.x) * vg.x;
    vfin.y = v0.y + (vf.y - v0.y) * vg.y;
    vfin.z = v0.z + (vf.z - v0.z) * vg.z;
    vfin.w = v0.w + (vf.w - v0.w) * vg.w;
    *(float4*)(v_buf + base) = vfin;

    float4 wd;
    wd.x = __expf(DECAY_C * sigm(wl.x));
    wd.y = __expf(DECAY_C * sigm(wl.y));
    wd.z = __expf(DECAY_C * sigm(wl.z));
    wd.w = __expf(DECAY_C * sigm(wl.w));
    *(float4*)(wl_buf + base) = wd;
}

// ---------------- sequential scan, row-split + chunked staging (round-4 shape)
// grid (64 bh, 4 rowgroups), 256 threads = 4 waves: 16 rows x 16 lanes,
// 4 state elems/thread. Reductions via DPP row_ror rotate-adds (VALU pipe) —
// the LDS pipe carries only the 6 staging reads per thread-step.
__global__ __launch_bounds__(256)
void scan_kernel(const float* __restrict__ r_buf, const float* __restrict__ w_buf,
                 const float* __restrict__ k_buf, const float* __restrict__ kkn_buf,
                 const float* __restrict__ a_buf, const float* __restrict__ v_buf,
                 float* __restrict__ out_scan, float* __restrict__ state_out)
{
    __shared__ float vec[16][5][64];   // [t][r|w|k|kk|a][64]  20 KB
    __shared__ float vbuf[16][16];     // [t][16 rows]
    __shared__ float ybuf[16][16];     // [t][16 rows]
    const int bh = blockIdx.x;
    const int rg = blockIdx.y;
    const int b = bh >> 4, h = bh & 15;
    const int tid = threadIdx.x;
    const int row = tid >> 4, l16 = tid & 15;
    const int rowbase = rg * 16;
    const size_t tok0 = ((size_t)b * 1024) * DD + h * HSZ;
    float s0 = 0.f, s1 = 0.f, s2 = 0.f, s3 = 0.f;

    const int tld = tid >> 4;          // which t this thread stages
    const int lld = (tid & 15) * 4;    // element offset in the 64-vec
    const int ft = tid >> 2, fl = (tid & 3) * 4;  // flush/vbuf map (tid<64)

    for (int c = 0; c < 64; c++) {
        if (c > 0 && tid < 64) {
            float4 yv = *(float4*)&ybuf[ft][fl];
            *(float4*)(out_scan + tok0 + (size_t)((c - 1) * 16 + ft) * DD + rowbase + fl) = yv;
        }
#pragma unroll
        for (int j = 0; j < 5; j++) {
            const float* bs = (j == 0) ? r_buf : (j == 1) ? w_buf : (j == 2) ? k_buf
                              : (j == 3) ? kkn_buf : a_buf;
            *(float4*)&vec[tld][j][lld] =
                *(const float4*)(bs + tok0 + (size_t)(c * 16 + tld) * DD + lld);
        }
        if (tid < 64) {
            *(float4*)&vbuf[ft][fl] =
                *(const float4*)(v_buf + tok0 + (size_t)(c * 16 + ft) * DD + rowbase + fl);
        }
        __syncthreads();

        for (int t = 0; t < 16; t++) {
            const float* vp = &vec[t][0][0];
            float4 r4 = *(const float4*)(vp + l16 * 4);
            float4 w4 = *(const float4*)(vp + 64 + l16 * 4);
            float4 k4 = *(const float4*)(vp + 128 + l16 * 4);
            float4 q4 = *(const float4*)(vp + 192 + l16 * 4);  // kk
            float4 a4 = *(const float4*)(vp + 256 + l16 * 4);
            float vv = vbuf[t][row];

            float sa = s0 * q4.x + s1 * q4.y + s2 * q4.z + s3 * q4.w;
            sa = row_sum16(sa);
            sa = -sa;  // at = -kk

            s0 = s0 * w4.x + sa * (q4.x * a4.x) + vv * k4.x;
            s1 = s1 * w4.y + sa * (q4.y * a4.y) + vv * k4.y;
            s2 = s2 * w4.z + sa * (q4.z * a4.z) + vv * k4.z;
            s3 = s3 * w4.w + sa * (q4.w * a4.w) + vv * k4.w;

            float y = s0 * r4.x + s1 * r4.y + s2 * r4.z + s3 * r4.w;
            y = row_sum16(y);
            if (l16 == 0) ybuf[t][row] = y;
        }
        __syncthreads();
    }

    // final flush (chunk 63)
    if (tid < 64) {
        float4 yv = *(float4*)&ybuf[ft][fl];
        *(float4*)(out_scan + tok0 + (size_t)(1008 + ft) * DD + rowbase + fl) = yv;
    }

    float* so = state_out + ((size_t)(b * NH + h) * HSZ + rowbase + row) * HSZ + l16 * 4;
    float4 sv = {s0, s1, s2, s3};
    *(float4*)so = sv;
}

// ---------------- stage 2: GroupNorm + residual + gate -> z (plain bf16)
__global__ __launch_bounds__(256)
void elemwise2(const float* __restrict__ out_scan, const float* __restrict__ rk_sum,
               const float* __restrict__ v_buf, const float* __restrict__ g_buf,
               const float* __restrict__ gscale, const float* __restrict__ gbias,
               ushort* __restrict__ z_buf)
{
    const int tok = blockIdx.x;
    const int tid = threadIdx.x;
    const int d0 = tid * 4;
    const size_t base = (size_t)tok * DD + d0;

    float4 o = *(const float4*)(out_scan + base);
    float sm = o.x + o.y + o.z + o.w;
    float ss = o.x * o.x + o.y * o.y + o.z * o.z + o.w * o.w;
    sm += __shfl_xor(sm, 1); sm += __shfl_xor(sm, 2);
    sm += __shfl_xor(sm, 4); sm += __shfl_xor(sm, 8);
    ss += __shfl_xor(ss, 1); ss += __shfl_xor(ss, 2);
    ss += __shfl_xor(ss, 4); ss += __shfl_xor(ss, 8);
    float mu = sm * (1.f / 64.f);
    float var = ss * (1.f / 64.f) - mu * mu;
    float rs = rsqrtf(var + GN_EPS);
    float rk = rk_sum[(size_t)tok * NH + (tid >> 4)];

    float4 v4 = *(const float4*)(v_buf + base);
    float4 g4 = *(const float4*)(g_buf + base);
    float4 gs = *(const float4*)(gscale + d0);
    float4 gb = *(const float4*)(gbias + d0);
    ushort4 z;
    z.x = f2bf(((o.x - mu) * rs * gs.x + gb.x + rk * v4.x) * g4.x);
    z.y = f2bf(((o.y - mu) * rs * gs.y + gb.y + rk * v4.y) * g4.y);
    z.z = f2bf(((o.z - mu) * rs * gs.z + gb.z + rk * v4.z) * g4.z);
    z.w = f2bf(((o.w - mu) * rs * gs.w + gb.w + rk * v4.w) * g4.w);
    *(ushort4*)(z_buf + base) = z;
}

extern "C" void kernel_launch(void* const* d_in, const int* in_sizes, int n_in,
                              void* d_out, int out_size, void* d_ws, size_t ws_size,
                              hipStream_t stream) {
    const float* cur    = (const float*)d_in[0];
    const float* prev   = (const float*)d_in[1];
    const float* vfirst = (const float*)d_in[2];
    const float* rwkvag = (const float*)d_in[3];
    const float* rw_W   = (const float*)d_in[4];
    const float* w1     = (const float*)d_in[5];
    const float* w2     = (const float*)d_in[6];
    const float* w2_b   = (const float*)d_in[7];
    const float* kw_W   = (const float*)d_in[8];
    const float* vw_W   = (const float*)d_in[9];
    const float* a1     = (const float*)d_in[10];
    const float* a2     = (const float*)d_in[11];
    const float* a2_b   = (const float*)d_in[12];
    const float* v1     = (const float*)d_in[13];
    const float* v2     = (const float*)d_in[14];
    const float* v2_b   = (const float*)d_in[15];
    const float* g1     = (const float*)d_in[16];
    const float* g2     = (const float*)d_in[17];
    const float* g2_b   = (const float*)d_in[18];
    const float* k_k    = (const float*)d_in[19];
    const float* k_a    = (const float*)d_in[20];
    const float* r_k    = (const float*)d_in[21];
    const float* gn_s   = (const float*)d_in[22];
    const float* gn_b   = (const float*)d_in[23];
    const float* out_W  = (const float*)d_in[24];

    float* out = (float*)d_out;
    float* y_out = out;                                  // 4096*1024 fp32
    float* state_out = out + (size_t)NT * DD;            // 4*16*64*64 fp32
    float* vf_out = state_out + (size_t)4 * NH * HSZ * HSZ;

    // ---- workspace carve (float units). ~166 MB total.
    float* p = (float*)d_ws;
    const size_t big = (size_t)NT * DD;   // 4,194,304 floats
    const size_t half = big / 2;          // one big bf16 array, in float units
    float* r_buf = p;   p += big;
    float* w_buf = p;   p += big;   // wl -> wdec in place
    float* k_buf = p;   p += big;   // k0 -> k final in place
    float* v_buf = p;   p += big;   // v0 -> v final in place
    float* kkn_buf = p; p += big;
    float* a_buf = p;   p += big;
    float* vg_buf = p;  p += big;   // dead after elemwise1 -> reused as out_scan
    float* os_buf = vg_buf;
    float* g_buf = p;   p += big;
    ushort* xh = (ushort*)p; p += half;   // shared per-branch mix scratch
    ushort* xl = (ushort*)p; p += half;
    ushort* z_bf = xh;                    // z overlays xh (x dead post stage-1)
    const size_t WBIG = 524288;           // 1024x1024 bf16, float units
    ushort* rwTh = (ushort*)p; p += WBIG;  ushort* rwTl = (ushort*)p; p += WBIG;
    ushort* kwTh = (ushort*)p; p += WBIG;  ushort* kwTl = (ushort*)p; p += WBIG;
    ushort* vwTh = (ushort*)p; p += WBIG;  ushort* vwTl = (ushort*)p; p += WBIG;
    ushort* outTh = (ushort*)p; p += WBIG;              // plain (no lo)
    ushort* w1Th = (ushort*)p; p += 32768; ushort* w1Tl = (ushort*)p; p += 32768;
    ushort* a1Th = (ushort*)p; p += 32768; ushort* a1Tl = (ushort*)p; p += 32768;
    ushort* v1Th = (ushort*)p; p += 16384; ushort* v1Tl = (ushort*)p; p += 16384;
    ushort* g1Th = (ushort*)p; p += 65536;              // plain
    ushort* w2Th = (ushort*)p; p += 32768; ushort* w2Tl = (ushort*)p; p += 32768;
    ushort* a2Th = (ushort*)p; p += 32768; ushort* a2Tl = (ushort*)p; p += 32768;
    ushort* v2Th = (ushort*)p; p += 16384; ushort* v2Tl = (ushort*)p; p += 16384;
    ushort* g2Th = (ushort*)p; p += 65536;              // plain
    ushort* hwh = (ushort*)p; p += 131072; ushort* hwl = (ushort*)p; p += 131072;
    ushort* hah = (ushort*)p; p += 131072; ushort* hal = (ushort*)p; p += 131072;
    ushort* hvh = (ushort*)p; p += 65536;  ushort* hvl = (ushort*)p; p += 65536;
    ushort* hgh = (ushort*)p; p += 262144;              // plain
    float* rks_buf = p;        p += 65536;

    dim3 blk(256);
    dim3 t32x8(32, 8);

    // ---- weight transposes (split except g path / out_W)
    transpose_split<<<dim3(32, 32), t32x8, 0, stream>>>(rw_W, rwTh, rwTl, 1024, 1024);
    transpose_split<<<dim3(32, 32), t32x8, 0, stream>>>(kw_W, kwTh, kwTl, 1024, 1024);
    transpose_split<<<dim3(32, 32), t32x8, 0, stream>>>(vw_W, vwTh, vwTl, 1024, 1024);
    transpose_split<<<dim3(32, 32), t32x8, 0, stream>>>(out_W, outTh, nullptr, 1024, 1024);
    transpose_split<<<dim3(2, 32), t32x8, 0, stream>>>(w1, w1Th, w1Tl, 1024, 64);
    transpose_split<<<dim3(2, 32), t32x8, 0, stream>>>(a1, a1Th, a1Tl, 1024, 64);
    transpose_split<<<dim3(1, 32), t32x8, 0, stream>>>(v1, v1Th, v1Tl, 1024, 32);
    transpose_split<<<dim3(4, 32), t32x8, 0, stream>>>(g1, g1Th, nullptr, 1024, 128);
    transpose_split<<<dim3(32, 2), t32x8, 0, stream>>>(w2, w2Th, w2Tl, 64, 1024);
    transpose_split<<<dim3(32, 2), t32x8, 0, stream>>>(a2, a2Th, a2Tl, 64, 1024);
    transpose_split<<<dim3(32, 1), t32x8, 0, stream>>>(v2, v2Th, v2Tl, 32, 1024);
    transpose_split<<<dim3(32, 4), t32x8, 0, stream>>>(g2, g2Th, nullptr, 128, 1024);

    dim3 gBig(32, 8), gN1(32, 1);

    // ---- branch r
    mix_split<<<NT, blk, 0, stream>>>(cur, prev, rwkvag + 0 * DD, xh, xl);
    gemm_bf16s<<<gBig, blk, 0, stream>>>(xh, xl, rwTh, rwTl, nullptr, r_buf, nullptr, nullptr, 1024, 1024, 0);
    // ---- branch w (LoRA stage 1, tanh, split hidden)
    mix_split<<<NT, blk, 0, stream>>>(cur, prev, rwkvag + 1 * DD, xh, xl);
    gemm_bf16s<<<gN1, blk, 0, stream>>>(xh, xl, w1Th, w1Tl, nullptr, nullptr, hwh, hwl, 64, 1024, 1);
    // ---- branch k
    mix_split<<<NT, blk, 0, stream>>>(cur, prev, rwkvag + 2 * DD, xh, xl);
    gemm_bf16s<<<gBig, blk, 0, stream>>>(xh, xl, kwTh, kwTl, nullptr, k_buf, nullptr, nullptr, 1024, 1024, 0);
    // ---- branch v (big GEMM + v-gate LoRA stage 1)
    mix_split<<<NT, blk, 0, stream>>>(cur, prev, rwkvag + 3 * DD, xh, xl);
    gemm_bf16s<<<gBig, blk, 0, stream>>>(xh, xl, vwTh, vwTl, nullptr, v_buf, nullptr, nullptr, 1024, 1024, 0);
    gemm_bf16s<<<gN1, blk, 0, stream>>>(xh, xl, v1Th, v1Tl, nullptr, nullptr, hvh, hvl, 32, 1024, 0);
    // ---- branch a (LoRA stage 1)
    mix_split<<<NT, blk, 0, stream>>>(cur, prev, rwkvag + 4 * DD, xh, xl);
    gemm_bf16s<<<gN1, blk, 0, stream>>>(xh, xl, a1Th, a1Tl, nullptr, nullptr, hah, hal, 64, 1024, 0);
    // ---- branch g (plain bf16 path, sigmoid hidden)
    mix_split<<<NT, blk, 0, stream>>>(cur, prev, rwkvag + 5 * DD, xh, nullptr);
    gemm_bf16s<<<gN1, blk, 0, stream>>>(xh, nullptr, g1Th, nullptr, nullptr, nullptr, hgh, nullptr, 128, 1024, 2);

    // ---- LoRA stage 2
    gemm_bf16s<<<gBig, blk, 0, stream>>>(hwh, hwl, w2Th, w2Tl, w2_b, w_buf, nullptr, nullptr, 1024, 64, 0);
    gemm_bf16s<<<gBig, blk, 0, stream>>>(hah, hal, a2Th, a2Tl, a2_b, a_buf, nullptr, nullptr, 1024, 64, 2);
    gemm_bf16s<<<gBig, blk, 0, stream>>>(hvh, hvl, v2Th, v2Tl, v2_b, vg_buf, nullptr, nullptr, 1024, 32, 2);
    gemm_bf16s<<<gBig, blk, 0, stream>>>(hgh, nullptr, g2Th, nullptr, g2_b, g_buf, nullptr, nullptr, 1024, 128, 0);

    // ---- elementwise + scan + epilogue
    elemwise1<<<NT, blk, 0, stream>>>(r_buf, w_buf, k_buf, v_buf, kkn_buf, a_buf,
                                      vg_buf, vfirst, k_k, k_a, r_k, rks_buf);

    scan_kernel<<<dim3(64, 4), blk, 0, stream>>>(r_buf, w_buf, k_buf, kkn_buf, a_buf, v_buf,
                                                 os_buf, state_out);

    elemwise2<<<NT, blk, 0, stream>>>(os_buf, rks_buf, v_buf, g_buf, gn_s, gn_b, z_bf);

    // ---- y = z @ out_W (plain bf16)
    gemm_bf16s<<<gBig, blk, 0, stream>>>(z_bf, nullptr, outTh, nullptr, nullptr, y_out, nullptr, nullptr, 1024, 1024, 0);

    // ---- v_first passthrough
    hipMemcpyAsync(vf_out, vfirst, (size_t)NT * DD * sizeof(float),
                   hipMemcpyDeviceToDevice, stream);
}

// Round 7
// 605.079 us; speedup vs baseline: 2.0816x; 1.4469x over previous
//
#include <hip/hip_runtime.h>
#include <math.h>

#define NT 4096      // B*T
#define DD 1024      // D == DM
#define NH 16
#define HSZ 64
#define GN_EPS 1e-5f
#define DECAY_C -0.606531f

typedef __attribute__((ext_vector_type(8))) short short8;
typedef __attribute__((ext_vector_type(4))) float float4v;

#define GLB(p) ((const __attribute__((address_space(1))) void*)(p))
#define LDS(p) ((__attribute__((address_space(3))) void*)(p))

__device__ __forceinline__ float sigm(float x) { return 1.f / (1.f + __expf(-x)); }

__device__ __forceinline__ unsigned short f2bf(float f) {
    unsigned int u = __float_as_uint(f);
    u = (u + 0x7fffu + ((u >> 16) & 1u)) >> 16;
    return (unsigned short)u;
}
__device__ __forceinline__ float bf2f(unsigned short h) {
    return __uint_as_float(((unsigned int)h) << 16);
}

// Full sum across each 16-lane row via DPP row_ror rotate-adds (VALU pipe only)
__device__ __forceinline__ float row_sum16(float x) {
    int t;
    t = __builtin_amdgcn_update_dpp(0, __float_as_int(x), 0x128, 0xF, 0xF, true); // ror 8
    x += __int_as_float(t);
    t = __builtin_amdgcn_update_dpp(0, __float_as_int(x), 0x124, 0xF, 0xF, true); // ror 4
    x += __int_as_float(t);
    t = __builtin_amdgcn_update_dpp(0, __float_as_int(x), 0x122, 0xF, 0xF, true); // ror 2
    x += __int_as_float(t);
    t = __builtin_amdgcn_update_dpp(0, __float_as_int(x), 0x121, 0xF, 0xF, true); // ror 1
    x += __int_as_float(t);
    return x;
}

// ---------------- fused 6-branch mix + hi/lo split-cast
__global__ __launch_bounds__(256)
void mix6(const float* __restrict__ cur, const float* __restrict__ prev,
          const float* __restrict__ lam,
          ushort* __restrict__ xrh, ushort* __restrict__ xrl,
          ushort* __restrict__ xwh, ushort* __restrict__ xwl,
          ushort* __restrict__ xkh, ushort* __restrict__ xkl,
          ushort* __restrict__ xvh, ushort* __restrict__ xvl,
          ushort* __restrict__ xah, ushort* __restrict__ xal,
          ushort* __restrict__ xgh, ushort* __restrict__ xgl)
{
    const int tok = blockIdx.x;
    const int d0 = threadIdx.x * 4;
    const size_t base = (size_t)tok * DD + d0;
    float4 c = *(const float4*)(cur + base);
    float4 p = *(const float4*)(prev + base);
    float dx = p.x - c.x, dy = p.y - c.y, dz = p.z - c.z, dw = p.w - c.w;
    ushort* hs[6] = {xrh, xwh, xkh, xvh, xah, xgh};
    ushort* ls[6] = {xrl, xwl, xkl, xvl, xal, xgl};
#pragma unroll
    for (int j = 0; j < 6; j++) {
        float4 l = *(const float4*)(lam + j * DD + d0);
        float m0 = c.x + l.x * dx;
        float m1 = c.y + l.y * dy;
        float m2 = c.z + l.z * dz;
        float m3 = c.w + l.w * dw;
        ushort4 h;
        h.x = f2bf(m0); h.y = f2bf(m1); h.z = f2bf(m2); h.w = f2bf(m3);
        *(ushort4*)(hs[j] + base) = h;
        ushort4 lo;
        lo.x = f2bf(m0 - bf2f(h.x));
        lo.y = f2bf(m1 - bf2f(h.y));
        lo.z = f2bf(m2 - bf2f(h.z));
        lo.w = f2bf(m3 - bf2f(h.w));
        *(ushort4*)(ls[j] + base) = lo;
    }
}

// ---------------- transpose + split-cast with zero-padding:
// W[K][N] fp32 -> Wt[Npad][K] hi/lo bf16. grid.x covers Npad/32; cols >= N -> 0.
__global__ __launch_bounds__(256)
void transpose_pad(const float* __restrict__ W, ushort* __restrict__ Wh,
                   ushort* __restrict__ Wl, int K, int N)
{
    __shared__ float tile[32][33];
    const int bx = blockIdx.x * 32;  // N (padded)
    const int by = blockIdx.y * 32;  // K
    const int tx = threadIdx.x, ty = threadIdx.y;  // 32 x 8
#pragma unroll
    for (int i = 0; i < 32; i += 8) {
        float v = 0.f;
        if (bx + tx < N) v = W[(size_t)(by + ty + i) * N + bx + tx];
        tile[ty + i][tx] = v;
    }
    __syncthreads();
#pragma unroll
    for (int i = 0; i < 32; i += 8) {
        float v = tile[tx][ty + i];
        ushort h = f2bf(v);
        size_t o = (size_t)(bx + ty + i) * K + by + tx;
        Wh[o] = h;
        if (Wl) Wl[o] = f2bf(v - bf2f(h));
    }
}

// ---------------- MEGA stage-1 GEMM: all 7 branch products in one dispatch.
// N = 3584 = r[0,1024) k[1024,2048) v[2048,3072) w1@3072(64) a1@3200(64)
//            v1@3328(32) g1@3456(128). K=1024, bf16x3 split, per-colblock A.
__global__ __launch_bounds__(256)
void gemm_mega1(const ushort* __restrict__ xrh, const ushort* __restrict__ xrl,
                const ushort* __restrict__ xwh, const ushort* __restrict__ xwl,
                const ushort* __restrict__ xkh, const ushort* __restrict__ xkl,
                const ushort* __restrict__ xvh, const ushort* __restrict__ xvl,
                const ushort* __restrict__ xah, const ushort* __restrict__ xal,
                const ushort* __restrict__ xgh, const ushort* __restrict__ xgl,
                const ushort* __restrict__ Bth, const ushort* __restrict__ Btl,
                float* __restrict__ r_buf, float* __restrict__ k_buf,
                float* __restrict__ v_buf,
                ushort* __restrict__ hwh, ushort* __restrict__ hwl,
                ushort* __restrict__ hah, ushort* __restrict__ hal,
                ushort* __restrict__ hvh, ushort* __restrict__ hvl,
                ushort* __restrict__ hgh, ushort* __restrict__ hgl)
{
    __shared__ ushort AsH[128 * 32];
    __shared__ ushort BsH[128 * 32];
    __shared__ ushort AsL[128 * 32];
    __shared__ ushort BsL[128 * 32];
    const int cb = blockIdx.y;
    const ushort* Ah; const ushort* Al;
    if (cb < 8)       { Ah = xrh; Al = xrl; }
    else if (cb < 16) { Ah = xkh; Al = xkl; }
    else if (cb < 24) { Ah = xvh; Al = xvl; }
    else if (cb == 24){ Ah = xwh; Al = xwl; }
    else if (cb == 25){ Ah = xah; Al = xal; }
    else if (cb == 26){ Ah = xvh; Al = xvl; }
    else              { Ah = xgh; Al = xgl; }

    const int tid = threadIdx.x;
    const int rowBase = blockIdx.x * 128;
    const int colBase = cb * 128;
    const int lane = tid & 63;
    const int wave = tid >> 6;
    const int wm = wave >> 1, wn = wave & 1;
    const int m15 = lane & 15, quad = lane >> 4;

    float4v zero4 = {0.f, 0.f, 0.f, 0.f};
    float4v acc[4][4];
#pragma unroll
    for (int i = 0; i < 4; i++)
#pragma unroll
        for (int j = 0; j < 4; j++) acc[i][j] = zero4;

    for (int k0 = 0; k0 < 1024; k0 += 32) {
#pragma unroll
        for (int i = 0; i < 2; i++) {
            int idx = i * 256 + tid;
            int r = idx >> 2, seg = idx & 3;
            size_t aoff = (size_t)(rowBase + r) * 1024 + k0 + seg * 8;
            size_t boff = (size_t)(colBase + r) * 1024 + k0 + seg * 8;
            int dst = (i * 256 + (tid & ~63)) * 8;
            __builtin_amdgcn_global_load_lds(GLB(Ah + aoff), LDS(AsH + dst), 16, 0, 0);
            __builtin_amdgcn_global_load_lds(GLB(Bth + boff), LDS(BsH + dst), 16, 0, 0);
            __builtin_amdgcn_global_load_lds(GLB(Al + aoff), LDS(AsL + dst), 16, 0, 0);
            __builtin_amdgcn_global_load_lds(GLB(Btl + boff), LDS(BsL + dst), 16, 0, 0);
        }
        __syncthreads();
        short8 ah[4], bh[4], al[4], bl[4];
#pragma unroll
        for (int mi = 0; mi < 4; mi++) {
            ah[mi] = *(const short8*)(AsH + (wm * 64 + mi * 16 + m15) * 32 + quad * 8);
            al[mi] = *(const short8*)(AsL + (wm * 64 + mi * 16 + m15) * 32 + quad * 8);
        }
#pragma unroll
        for (int ni = 0; ni < 4; ni++) {
            bh[ni] = *(const short8*)(BsH + (wn * 64 + ni * 16 + m15) * 32 + quad * 8);
            bl[ni] = *(const short8*)(BsL + (wn * 64 + ni * 16 + m15) * 32 + quad * 8);
        }
#pragma unroll
        for (int mi = 0; mi < 4; mi++)
#pragma unroll
            for (int ni = 0; ni < 4; ni++) {
                acc[mi][ni] = __builtin_amdgcn_mfma_f32_16x16x32_bf16(al[mi], bh[ni], acc[mi][ni], 0, 0, 0);
                acc[mi][ni] = __builtin_amdgcn_mfma_f32_16x16x32_bf16(ah[mi], bl[ni], acc[mi][ni], 0, 0, 0);
                acc[mi][ni] = __builtin_amdgcn_mfma_f32_16x16x32_bf16(ah[mi], bh[ni], acc[mi][ni], 0, 0, 0);
            }
        __syncthreads();
    }

#pragma unroll
    for (int mi = 0; mi < 4; mi++) {
#pragma unroll
        for (int ni = 0; ni < 4; ni++) {
            int c = wn * 64 + ni * 16 + m15;   // col within 128-tile
#pragma unroll
            for (int rr = 0; rr < 4; rr++) {
                int row = rowBase + wm * 64 + mi * 16 + quad * 4 + rr;
                float v = acc[mi][ni][rr];
                if (cb < 24) {
                    float* dst = (cb < 8) ? r_buf : (cb < 16) ? k_buf : v_buf;
                    int n = (cb & 7) * 128 + c;
                    dst[(size_t)row * 1024 + n] = v;
                } else if (cb == 24) {
                    if (c < 64) {
                        float t = tanhf(v);
                        ushort h = f2bf(t);
                        hwh[(size_t)row * 64 + c] = h;
                        hwl[(size_t)row * 64 + c] = f2bf(t - bf2f(h));
                    }
                } else if (cb == 25) {
                    if (c < 64) {
                        ushort h = f2bf(v);
                        hah[(size_t)row * 64 + c] = h;
                        hal[(size_t)row * 64 + c] = f2bf(v - bf2f(h));
                    }
                } else if (cb == 26) {
                    if (c < 32) {
                        ushort h = f2bf(v);
                        hvh[(size_t)row * 32 + c] = h;
                        hvl[(size_t)row * 32 + c] = f2bf(v - bf2f(h));
                    }
                } else {
                    float t = sigm(v);
                    ushort h = f2bf(t);
                    hgh[(size_t)row * 128 + c] = h;
                    hgl[(size_t)row * 128 + c] = f2bf(t - bf2f(h));
                }
            }
        }
    }
}

// ---------------- MEGA stage-2 GEMM: 4 LoRA stage-2 products in one dispatch.
// blockIdx.y: 0-7 w2(K=64,none), 8-15 a2(K=64,sigm), 16-23 v2(K=32,sigm),
// 24-31 g2(K=128,none). All outputs fp32 [4096][1024].
__global__ __launch_bounds__(256)
void gemm_mega2(const ushort* __restrict__ hwh, const ushort* __restrict__ hwl,
                const ushort* __restrict__ hah, const ushort* __restrict__ hal,
                const ushort* __restrict__ hvh, const ushort* __restrict__ hvl,
                const ushort* __restrict__ hgh, const ushort* __restrict__ hgl,
                const ushort* __restrict__ w2Th, const ushort* __restrict__ w2Tl,
                const ushort* __restrict__ a2Th, const ushort* __restrict__ a2Tl,
                const ushort* __restrict__ v2Th, const ushort* __restrict__ v2Tl,
                const ushort* __restrict__ g2Th, const ushort* __restrict__ g2Tl,
                const float* __restrict__ w2_b, const float* __restrict__ a2_b,
                const float* __restrict__ v2_b, const float* __restrict__ g2_b,
                float* __restrict__ w_buf, float* __restrict__ a_buf,
                float* __restrict__ vg_buf, float* __restrict__ g_buf)
{
    __shared__ ushort AsH[128 * 32];
    __shared__ ushort BsH[128 * 32];
    __shared__ ushort AsL[128 * 32];
    __shared__ ushort BsL[128 * 32];
    const int cb = blockIdx.y;
    const int seg = cb >> 3;
    const int K = (seg == 2) ? 32 : (seg == 3) ? 128 : 64;
    const ushort *Ah, *Al, *Bh, *Bl;
    const float* bias;
    float* outp;
    if (seg == 0) { Ah = hwh; Al = hwl; Bh = w2Th; Bl = w2Tl; bias = w2_b; outp = w_buf; }
    else if (seg == 1) { Ah = hah; Al = hal; Bh = a2Th; Bl = a2Tl; bias = a2_b; outp = a_buf; }
    else if (seg == 2) { Ah = hvh; Al = hvl; Bh = v2Th; Bl = v2Tl; bias = v2_b; outp = vg_buf; }
    else { Ah = hgh; Al = hgl; Bh = g2Th; Bl = g2Tl; bias = g2_b; outp = g_buf; }

    const int tid = threadIdx.x;
    const int rowBase = blockIdx.x * 128;
    const int colBase = (cb & 7) * 128;
    const int lane = tid & 63;
    const int wave = tid >> 6;
    const int wm = wave >> 1, wn = wave & 1;
    const int m15 = lane & 15, quad = lane >> 4;

    float4v zero4 = {0.f, 0.f, 0.f, 0.f};
    float4v acc[4][4];
#pragma unroll
    for (int i = 0; i < 4; i++)
#pragma unroll
        for (int j = 0; j < 4; j++) acc[i][j] = zero4;

    for (int k0 = 0; k0 < K; k0 += 32) {
#pragma unroll
        for (int i = 0; i < 2; i++) {
            int idx = i * 256 + tid;
            int r = idx >> 2, s8 = idx & 3;
            size_t aoff = (size_t)(rowBase + r) * K + k0 + s8 * 8;
            size_t boff = (size_t)(colBase + r) * K + k0 + s8 * 8;
            int dst = (i * 256 + (tid & ~63)) * 8;
            __builtin_amdgcn_global_load_lds(GLB(Ah + aoff), LDS(AsH + dst), 16, 0, 0);
            __builtin_amdgcn_global_load_lds(GLB(Bh + boff), LDS(BsH + dst), 16, 0, 0);
            __builtin_amdgcn_global_load_lds(GLB(Al + aoff), LDS(AsL + dst), 16, 0, 0);
            __builtin_amdgcn_global_load_lds(GLB(Bl + boff), LDS(BsL + dst), 16, 0, 0);
        }
        __syncthreads();
        short8 ah[4], bh[4], al[4], bl[4];
#pragma unroll
        for (int mi = 0; mi < 4; mi++) {
            ah[mi] = *(const short8*)(AsH + (wm * 64 + mi * 16 + m15) * 32 + quad * 8);
            al[mi] = *(const short8*)(AsL + (wm * 64 + mi * 16 + m15) * 32 + quad * 8);
        }
#pragma unroll
        for (int ni = 0; ni < 4; ni++) {
            bh[ni] = *(const short8*)(BsH + (wn * 64 + ni * 16 + m15) * 32 + quad * 8);
            bl[ni] = *(const short8*)(BsL + (wn * 64 + ni * 16 + m15) * 32 + quad * 8);
        }
#pragma unroll
        for (int mi = 0; mi < 4; mi++)
#pragma unroll
            for (int ni = 0; ni < 4; ni++) {
                acc[mi][ni] = __builtin_amdgcn_mfma_f32_16x16x32_bf16(al[mi], bh[ni], acc[mi][ni], 0, 0, 0);
                acc[mi][ni] = __builtin_amdgcn_mfma_f32_16x16x32_bf16(ah[mi], bl[ni], acc[mi][ni], 0, 0, 0);
                acc[mi][ni] = __builtin_amdgcn_mfma_f32_16x16x32_bf16(ah[mi], bh[ni], acc[mi][ni], 0, 0, 0);
            }
        __syncthreads();
    }

#pragma unroll
    for (int mi = 0; mi < 4; mi++) {
#pragma unroll
        for (int ni = 0; ni < 4; ni++) {
            int col = colBase + wn * 64 + ni * 16 + m15;
            float bv = bias[col];
#pragma unroll
            for (int rr = 0; rr < 4; rr++) {
                int row = rowBase + wm * 64 + mi * 16 + quad * 4 + rr;
                float v = acc[mi][ni][rr] + bv;
                if (seg == 1 || seg == 2) v = sigm(v);
                outp[(size_t)row * 1024 + col] = v;
            }
        }
    }
}

// ---------------- plain/split bf16 GEMM (final out-projection)
__global__ __launch_bounds__(256)
void gemm_bf16s(const ushort* __restrict__ Ah, const ushort* __restrict__ Bh,
                float* __restrict__ outF, int N, int K)
{
    __shared__ ushort AsH[128 * 32];
    __shared__ ushort BsH[128 * 32];
    const int tid = threadIdx.x;
    const int rowBase = blockIdx.x * 128;
    const int colBase = blockIdx.y * 128;
    const int lane = tid & 63;
    const int wave = tid >> 6;
    const int wm = wave >> 1, wn = wave & 1;
    const int m15 = lane & 15, quad = lane >> 4;

    float4v zero4 = {0.f, 0.f, 0.f, 0.f};
    float4v acc[4][4];
#pragma unroll
    for (int i = 0; i < 4; i++)
#pragma unroll
        for (int j = 0; j < 4; j++) acc[i][j] = zero4;

    for (int k0 = 0; k0 < K; k0 += 32) {
#pragma unroll
        for (int i = 0; i < 2; i++) {
            int idx = i * 256 + tid;
            int r = idx >> 2, seg = idx & 3;
            size_t aoff = (size_t)(rowBase + r) * K + k0 + seg * 8;
            size_t boff = (size_t)(colBase + r) * K + k0 + seg * 8;
            int dst = (i * 256 + (tid & ~63)) * 8;
            __builtin_amdgcn_global_load_lds(GLB(Ah + aoff), LDS(AsH + dst), 16, 0, 0);
            __builtin_amdgcn_global_load_lds(GLB(Bh + boff), LDS(BsH + dst), 16, 0, 0);
        }
        __syncthreads();
        short8 ah[4], bh[4];
#pragma unroll
        for (int mi = 0; mi < 4; mi++)
            ah[mi] = *(const short8*)(AsH + (wm * 64 + mi * 16 + m15) * 32 + quad * 8);
#pragma unroll
        for (int ni = 0; ni < 4; ni++)
            bh[ni] = *(const short8*)(BsH + (wn * 64 + ni * 16 + m15) * 32 + quad * 8);
#pragma unroll
        for (int mi = 0; mi < 4; mi++)
#pragma unroll
            for (int ni = 0; ni < 4; ni++)
                acc[mi][ni] = __builtin_amdgcn_mfma_f32_16x16x32_bf16(ah[mi], bh[ni], acc[mi][ni], 0, 0, 0);
        __syncthreads();
    }

#pragma unroll
    for (int mi = 0; mi < 4; mi++) {
#pragma unroll
        for (int ni = 0; ni < 4; ni++) {
            int col = colBase + wn * 64 + ni * 16 + m15;
#pragma unroll
            for (int rr = 0; rr < 4; rr++) {
                int row = rowBase + wm * 64 + mi * 16 + quad * 4 + rr;
                outF[(size_t)row * N + col] = acc[mi][ni][rr];
            }
        }
    }
}

// ---------------- elementwise stage 1 (fp32)
__global__ __launch_bounds__(256)
void elemwise1(const float* __restrict__ r_buf, float* __restrict__ wl_buf,
               float* __restrict__ k_buf, float* __restrict__ v_buf,
               float* __restrict__ kkn_buf, const float* __restrict__ a_buf,
               const float* __restrict__ vg_buf, const float* __restrict__ vfirst,
               const float* __restrict__ kkw, const float* __restrict__ kaw,
               const float* __restrict__ rkw, float* __restrict__ rk_sum)
{
    const int tok = blockIdx.x;
    const int tid = threadIdx.x;
    const int d0 = tid * 4;
    const size_t base = (size_t)tok * DD + d0;

    float4 k0 = *(const float4*)(k_buf + base);
    float4 a4 = *(const float4*)(a_buf + base);
    float4 wl = *(const float4*)(wl_buf + base);
    float4 v0 = *(const float4*)(v_buf + base);
    float4 vg = *(const float4*)(vg_buf + base);
    float4 vf = *(const float4*)(vfirst + base);
    float4 r4 = *(const float4*)(r_buf + base);
    float4 kkc = *(const float4*)(kkw + d0);
    float4 kac = *(const float4*)(kaw + d0);
    float4 rkc = *(const float4*)(rkw + d0);

    float kk0 = k0.x * kkc.x, kk1 = k0.y * kkc.y, kk2 = k0.z * kkc.z, kk3 = k0.w * kkc.w;
    float ss = kk0 * kk0 + kk1 * kk1 + kk2 * kk2 + kk3 * kk3;
    ss += __shfl_xor(ss, 1); ss += __shfl_xor(ss, 2);
    ss += __shfl_xor(ss, 4); ss += __shfl_xor(ss, 8);
    float rn = rsqrtf(ss);
    float4 kkn = { kk0 * rn, kk1 * rn, kk2 * rn, kk3 * rn };
    *(float4*)(kkn_buf + base) = kkn;

    float4 kf;
    kf.x = k0.x * (1.f + (a4.x - 1.f) * kac.x);
    kf.y = k0.y * (1.f + (a4.y - 1.f) * kac.y);
    kf.z = k0.z * (1.f + (a4.z - 1.f) * kac.z);
    kf.w = k0.w * (1.f + (a4.w - 1.f) * kac.w);
    *(float4*)(k_buf + base) = kf;

    float rk = r4.x * kf.x * rkc.x + r4.y * kf.y * rkc.y + r4.z * kf.z * rkc.z + r4.w * kf.w * rkc.w;
    rk += __shfl_xor(rk, 1); rk += __shfl_xor(rk, 2);
    rk += __shfl_xor(rk, 4); rk += __shfl_xor(rk, 8);
    if ((tid & 15) == 0) rk_sum[(size_t)tok * NH + (tid >> 4)] = rk;

    float4 vfin;
    vfin.x = v0.x + (vf.x - v0.x) * vg.x;
    vfin.y = v0.y + (vf.y - v0.y) * vg.y;
    vfin.z = v0.z + (vf.z - v0.z) * vg.z;
    vfin.w = v0.w + (vf.w - v0.w) * vg.w;
    *(float4*)(v_buf + base) = vfin;

    float4 wd;
    wd.x = __expf(DECAY_C * sigm(wl.x));
    wd.y = __expf(DECAY_C * sigm(wl.y));
    wd.z = __expf(DECAY_C * sigm(wl.z));
    wd.w = __expf(DECAY_C * sigm(wl.w));
    *(float4*)(wl_buf + base) = wd;
}

// ---------------- sequential scan (round-6 structure, DPP reductions)
__global__ __launch_bounds__(256)
void scan_kernel(const float* __restrict__ r_buf, const float* __restrict__ w_buf,
                 const float* __restrict__ k_buf, const float* __restrict__ kkn_buf,
                 const float* __restrict__ a_buf, const float* __restrict__ v_buf,
                 float* __restrict__ out_scan, float* __restrict__ state_out)
{
    __shared__ float vec[16][5][64];
    __shared__ float vbuf[16][16];
    __shared__ float ybuf[16][16];
    const int bh = blockIdx.x;
    const int rg = blockIdx.y;
    const int b = bh >> 4, h = bh & 15;
    const int tid = threadIdx.x;
    const int row = tid >> 4, l16 = tid & 15;
    const int rowbase = rg * 16;
    const size_t tok0 = ((size_t)b * 1024) * DD + h * HSZ;
    float s0 = 0.f, s1 = 0.f, s2 = 0.f, s3 = 0.f;

    const int tld = tid >> 4;
    const int lld = (tid & 15) * 4;
    const int ft = tid >> 2, fl = (tid & 3) * 4;

    for (int c = 0; c < 64; c++) {
        if (c > 0 && tid < 64) {
            float4 yv = *(float4*)&ybuf[ft][fl];
            *(float4*)(out_scan + tok0 + (size_t)((c - 1) * 16 + ft) * DD + rowbase + fl) = yv;
        }
#pragma unroll
        for (int j = 0; j < 5; j++) {
            const float* bs = (j == 0) ? r_buf : (j == 1) ? w_buf : (j == 2) ? k_buf
                              : (j == 3) ? kkn_buf : a_buf;
            *(float4*)&vec[tld][j][lld] =
                *(const float4*)(bs + tok0 + (size_t)(c * 16 + tld) * DD + lld);
        }
        if (tid < 64) {
            *(float4*)&vbuf[ft][fl] =
                *(const float4*)(v_buf + tok0 + (size_t)(c * 16 + ft) * DD + rowbase + fl);
        }
        __syncthreads();

        for (int t = 0; t < 16; t++) {
            const float* vp = &vec[t][0][0];
            float4 r4 = *(const float4*)(vp + l16 * 4);
            float4 w4 = *(const float4*)(vp + 64 + l16 * 4);
            float4 k4 = *(const float4*)(vp + 128 + l16 * 4);
            float4 q4 = *(const float4*)(vp + 192 + l16 * 4);
            float4 a4 = *(const float4*)(vp + 256 + l16 * 4);
            float vv = vbuf[t][row];

            float sa = s0 * q4.x + s1 * q4.y + s2 * q4.z + s3 * q4.w;
            sa = row_sum16(sa);
            sa = -sa;

            s0 = s0 * w4.x + sa * (q4.x * a4.x) + vv * k4.x;
            s1 = s1 * w4.y + sa * (q4.y * a4.y) + vv * k4.y;
            s2 = s2 * w4.z + sa * (q4.z * a4.z) + vv * k4.z;
            s3 = s3 * w4.w + sa * (q4.w * a4.w) + vv * k4.w;

            float y = s0 * r4.x + s1 * r4.y + s2 * r4.z + s3 * r4.w;
            y = row_sum16(y);
            if (l16 == 0) ybuf[t][row] = y;
        }
        __syncthreads();
    }

    if (tid < 64) {
        float4 yv = *(float4*)&ybuf[ft][fl];
        *(float4*)(out_scan + tok0 + (size_t)(1008 + ft) * DD + rowbase + fl) = yv;
    }

    float* so = state_out + ((size_t)(b * NH + h) * HSZ + rowbase + row) * HSZ + l16 * 4;
    float4 sv = {s0, s1, s2, s3};
    *(float4*)so = sv;
}

// ---------------- stage 2: GroupNorm + residual + gate -> z (plain bf16)
__global__ __launch_bounds__(256)
void elemwise2(const float* __restrict__ out_scan, const float* __restrict__ rk_sum,
               const float* __restrict__ v_buf, const float* __restrict__ g_buf,
               const float* __restrict__ gscale, const float* __restrict__ gbias,
               ushort* __restrict__ z_buf)
{
    const int tok = blockIdx.x;
    const int tid = threadIdx.x;
    const int d0 = tid * 4;
    const size_t base = (size_t)tok * DD + d0;

    float4 o = *(const float4*)(out_scan + base);
    float sm = o.x + o.y + o.z + o.w;
    float ss = o.x * o.x + o.y * o.y + o.z * o.z + o.w * o.w;
    sm += __shfl_xor(sm, 1); sm += __shfl_xor(sm, 2);
    sm += __shfl_xor(sm, 4); sm += __shfl_xor(sm, 8);
    ss += __shfl_xor(ss, 1); ss += __shfl_xor(ss, 2);
    ss += __shfl_xor(ss, 4); ss += __shfl_xor(ss, 8);
    float mu = sm * (1.f / 64.f);
    float var = ss * (1.f / 64.f) - mu * mu;
    float rs = rsqrtf(var + GN_EPS);
    float rk = rk_sum[(size_t)tok * NH + (tid >> 4)];

    float4 v4 = *(const float4*)(v_buf + base);
    float4 g4 = *(const float4*)(g_buf + base);
    float4 gs = *(const float4*)(gscale + d0);
    float4 gb = *(const float4*)(gbias + d0);
    ushort4 z;
    z.x = f2bf(((o.x - mu) * rs * gs.x + gb.x + rk * v4.x) * g4.x);
    z.y = f2bf(((o.y - mu) * rs * gs.y + gb.y + rk * v4.y) * g4.y);
    z.z = f2bf(((o.z - mu) * rs * gs.z + gb.z + rk * v4.z) * g4.z);
    z.w = f2bf(((o.w - mu) * rs * gs.w + gb.w + rk * v4.w) * g4.w);
    *(ushort4*)(z_buf + base) = z;
}

extern "C" void kernel_launch(void* const* d_in, const int* in_sizes, int n_in,
                              void* d_out, int out_size, void* d_ws, size_t ws_size,
                              hipStream_t stream) {
    const float* cur    = (const float*)d_in[0];
    const float* prev   = (const float*)d_in[1];
    const float* vfirst = (const float*)d_in[2];
    const float* rwkvag = (const float*)d_in[3];
    const float* rw_W   = (const float*)d_in[4];
    const float* w1     = (const float*)d_in[5];
    const float* w2     = (const float*)d_in[6];
    const float* w2_b   = (const float*)d_in[7];
    const float* kw_W   = (const float*)d_in[8];
    const float* vw_W   = (const float*)d_in[9];
    const float* a1     = (const float*)d_in[10];
    const float* a2     = (const float*)d_in[11];
    const float* a2_b   = (const float*)d_in[12];
    const float* v1     = (const float*)d_in[13];
    const float* v2     = (const float*)d_in[14];
    const float* v2_b   = (const float*)d_in[15];
    const float* g1     = (const float*)d_in[16];
    const float* g2     = (const float*)d_in[17];
    const float* g2_b   = (const float*)d_in[18];
    const float* k_k    = (const float*)d_in[19];
    const float* k_a    = (const float*)d_in[20];
    const float* r_k    = (const float*)d_in[21];
    const float* gn_s   = (const float*)d_in[22];
    const float* gn_b   = (const float*)d_in[23];
    const float* out_W  = (const float*)d_in[24];

    float* out = (float*)d_out;
    float* y_out = out;
    float* state_out = out + (size_t)NT * DD;
    float* vf_out = state_out + (size_t)4 * NH * HSZ * HSZ;

    // ---- workspace carve (float units). ~172 MB (same as round 6).
    float* p = (float*)d_ws;
    const size_t big = (size_t)NT * DD;   // 4,194,304
    const size_t half = big / 2;          // 2,097,152
    float* r_buf = p;   p += big;
    float* k_buf = p;   p += big;   // k0 -> k final in place
    float* v_buf = p;   p += big;   // v0 -> v final in place
    // x-region: 6 branch pairs (hi,lo), each pair = 'big' floats = 16 MB
    float* xreg = p;
    ushort* xrh = (ushort*)(xreg);            ushort* xrl = (ushort*)(xreg + half);
    ushort* xwh = (ushort*)(xreg + 2*half);   ushort* xwl = (ushort*)(xreg + 3*half);
    ushort* xkh = (ushort*)(xreg + 4*half);   ushort* xkl = (ushort*)(xreg + 5*half);
    ushort* xvh = (ushort*)(xreg + 6*half);   ushort* xvl = (ushort*)(xreg + 7*half);
    ushort* xah = (ushort*)(xreg + 8*half);   ushort* xal = (ushort*)(xreg + 9*half);
    ushort* xgh = (ushort*)(xreg + 10*half);  ushort* xgl = (ushort*)(xreg + 11*half);
    p += 12 * half;
    // overlays (valid after gemm_mega1 completes):
    float* w_buf   = xreg + 0 * half;   // wl -> wdec in place (16 MB over xr pair)
    float* a_buf   = xreg + 2 * half;   // over xw pair
    float* vg_buf  = xreg + 4 * half;   // over xk pair; reused as out_scan after E1
    float* os_buf  = vg_buf;
    float* g_buf   = xreg + 6 * half;   // over xv pair
    float* kkn_buf = xreg + 8 * half;   // over xa pair
    // Bt region: [3584][1024] bf16 hi + lo
    float* btreg = p;
    ushort* Bth = (ushort*)btreg;                      // 1,835,008 floats
    ushort* Btl = (ushort*)(btreg + 1835008);
    p += 2 * 1835008;
    // overlays on Bt region (valid after gemm_mega1):
    ushort* z_bf  = (ushort*)btreg;                    // 2,097,152 floats
    ushort* outTh = (ushort*)(btreg + 2097152);        // 524,288 floats
    // stage-2 transposed weights (hi/lo)
    ushort* w2Th = (ushort*)p; p += 32768; ushort* w2Tl = (ushort*)p; p += 32768;
    ushort* a2Th = (ushort*)p; p += 32768; ushort* a2Tl = (ushort*)p; p += 32768;
    ushort* v2Th = (ushort*)p; p += 16384; ushort* v2Tl = (ushort*)p; p += 16384;
    ushort* g2Th = (ushort*)p; p += 65536; ushort* g2Tl = (ushort*)p; p += 65536;
    // LoRA hidden buffers (hi/lo)
    ushort* hwh = (ushort*)p; p += 131072; ushort* hwl = (ushort*)p; p += 131072;
    ushort* hah = (ushort*)p; p += 131072; ushort* hal = (ushort*)p; p += 131072;
    ushort* hvh = (ushort*)p; p += 65536;  ushort* hvl = (ushort*)p; p += 65536;
    ushort* hgh = (ushort*)p; p += 262144; ushort* hgl = (ushort*)p; p += 262144;
    float* rks_buf = p;        p += 65536;

    dim3 blk(256);
    dim3 t32x8(32, 8);

    // ---- stage-1 B transposes into concatenated Bt [3584][1024]
    transpose_pad<<<dim3(32, 32), t32x8, 0, stream>>>(rw_W, Bth + (size_t)0 * 1024,    Btl + (size_t)0 * 1024,    1024, 1024);
    transpose_pad<<<dim3(32, 32), t32x8, 0, stream>>>(kw_W, Bth + (size_t)1024 * 1024, Btl + (size_t)1024 * 1024, 1024, 1024);
    transpose_pad<<<dim3(32, 32), t32x8, 0, stream>>>(vw_W, Bth + (size_t)2048 * 1024, Btl + (size_t)2048 * 1024, 1024, 1024);
    transpose_pad<<<dim3(4, 32), t32x8, 0, stream>>>(w1, Bth + (size_t)3072 * 1024, Btl + (size_t)3072 * 1024, 1024, 64);
    transpose_pad<<<dim3(4, 32), t32x8, 0, stream>>>(a1, Bth + (size_t)3200 * 1024, Btl + (size_t)3200 * 1024, 1024, 64);
    transpose_pad<<<dim3(4, 32), t32x8, 0, stream>>>(v1, Bth + (size_t)3328 * 1024, Btl + (size_t)3328 * 1024, 1024, 32);
    transpose_pad<<<dim3(4, 32), t32x8, 0, stream>>>(g1, Bth + (size_t)3456 * 1024, Btl + (size_t)3456 * 1024, 1024, 128);
    // stage-2 weights
    transpose_pad<<<dim3(32, 2), t32x8, 0, stream>>>(w2, w2Th, w2Tl, 64, 1024);
    transpose_pad<<<dim3(32, 2), t32x8, 0, stream>>>(a2, a2Th, a2Tl, 64, 1024);
    transpose_pad<<<dim3(32, 1), t32x8, 0, stream>>>(v2, v2Th, v2Tl, 32, 1024);
    transpose_pad<<<dim3(32, 4), t32x8, 0, stream>>>(g2, g2Th, g2Tl, 128, 1024);

    // ---- fused token-shift mixes (hi/lo) for all 6 branches
    mix6<<<NT, blk, 0, stream>>>(cur, prev, rwkvag,
                                 xrh, xrl, xwh, xwl, xkh, xkl,
                                 xvh, xvl, xah, xal, xgh, xgl);

    // ---- MEGA stage-1 GEMM (r,k,v + 4 LoRA stage-1)
    gemm_mega1<<<dim3(32, 28), blk, 0, stream>>>(
        xrh, xrl, xwh, xwl, xkh, xkl, xvh, xvl, xah, xal, xgh, xgl,
        Bth, Btl, r_buf, k_buf, v_buf,
        hwh, hwl, hah, hal, hvh, hvl, hgh, hgl);

    // out_W transpose (Bt region is free from here on)
    transpose_pad<<<dim3(32, 32), t32x8, 0, stream>>>(out_W, outTh, nullptr, 1024, 1024);

    // ---- MEGA stage-2 GEMM (w2/a2/v2/g2), overwrites x-region overlays
    gemm_mega2<<<dim3(32, 32), blk, 0, stream>>>(
        hwh, hwl, hah, hal, hvh, hvl, hgh, hgl,
        w2Th, w2Tl, a2Th, a2Tl, v2Th, v2Tl, g2Th, g2Tl,
        w2_b, a2_b, v2_b, g2_b,
        w_buf, a_buf, vg_buf, g_buf);

    // ---- elementwise + scan + epilogue
    elemwise1<<<NT, blk, 0, stream>>>(r_buf, w_buf, k_buf, v_buf, kkn_buf, a_buf,
                                      vg_buf, vfirst, k_k, k_a, r_k, rks_buf);

    scan_kernel<<<dim3(64, 4), blk, 0, stream>>>(r_buf, w_buf, k_buf, kkn_buf, a_buf, v_buf,
                                                 os_buf, state_out);

    elemwise2<<<NT, blk, 0, stream>>>(os_buf, rks_buf, v_buf, g_buf, gn_s, gn_b, z_bf);

    // ---- y = z @ out_W (plain bf16)
    gemm_bf16s<<<dim3(32, 8), blk, 0, stream>>>(z_bf, outTh, y_out, 1024, 1024);

    // ---- v_first passthrough
    hipMemcpyAsync(vf_out, vfirst, (size_t)NT * DD * sizeof(float),
                   hipMemcpyDeviceToDevice, stream);
}